// Round 21
// baseline (155.540 us; speedup 1.0000x reference)
//
#include <hip/hip_runtime.h>
#include <hip/hip_bf16.h>

// (B,H,S,D) = (2,8,4096,64)
#define S_   4096
#define D_   64
#define BH_  16
#define QW   64        // q rows per wave (two 32-col MFMA blocks)
#define QBLK 256       // q rows per block
#define KVB  128       // keys per staged tile (two 64-key halves per barrier)
#define NCH  2         // kv chunks (wave-halves of one block)

typedef __attribute__((ext_vector_type(8)))  short short8_t;   // 8 bf16 (MFMA A/B frag)
typedef __attribute__((ext_vector_type(16))) float f32x16;     // 32x32 MFMA C/D frag
#define QSCALE 0.18033688011112042f   /* (1/8)*log2(e): scores in log2 domain */

__device__ __forceinline__ unsigned short f2bf(float f) {
  unsigned u = __float_as_uint(f);
  u += 0x7fffu + ((u >> 16) & 1u);   // RTNE
  return (unsigned short)(u >> 16);
}

__device__ __forceinline__ void glds16(const unsigned short* g, unsigned short* l) {
  __builtin_amdgcn_global_load_lds(
      (const __attribute__((address_space(1))) unsigned int*)g,
      (__attribute__((address_space(3))) unsigned int*)l, 16, 0, 0);
}

// fused: per-batch mask scan (compact) + K/V gather + Q add/scale convert + V transpose.
__global__ void kvgather_kernel(const float* __restrict__ ka, const float* __restrict__ ks,
                                const float* __restrict__ va, const float* __restrict__ vs,
                                const float* __restrict__ qa, const float* __restrict__ qs,
                                const int* __restrict__ mask, int* __restrict__ cnt,
                                unsigned short* __restrict__ qhat,
                                unsigned short* __restrict__ khat,
                                unsigned short* __restrict__ vt) {
  __shared__ int ps[256];
  __shared__ int srcLds[64];
  __shared__ __align__(16) unsigned short t[D_][72];
  const int bh = blockIdx.y, b = bh >> 3;
  const int s0 = blockIdx.x * 64;
  const int tid = threadIdx.x;

  const int* mb = mask + (size_t)b * S_;
  int m[16], c = 0;
  const int base = tid * 16;
#pragma unroll
  for (int i = 0; i < 16; ++i) { m[i] = mb[base + i]; c += (m[i] != 0); }
  ps[tid] = c;
  __syncthreads();
  for (int off = 1; off < 256; off <<= 1) {   // Hillis-Steele inclusive scan
    int add = (tid >= off) ? ps[tid - off] : 0;
    __syncthreads();
    ps[tid] += add;
    __syncthreads();
  }
  const int C = ps[255];
  int pos = ps[tid] - c;   // exclusive prefix
#pragma unroll
  for (int i = 0; i < 16; ++i) {
    if (m[i]) {
      int r = pos++;
      if (r >= s0 && r < s0 + 64) srcLds[r - s0] = base + i;
    }
  }
  if (tid == 0 && blockIdx.x == 0 && (bh & 7) == 0) cnt[b] = C;
  __syncthreads();

  const int row16 = tid >> 4;
  const int col4  = (tid & 15) * 4;
#pragma unroll
  for (int p = 0; p < 4; ++p) {
    int srow = p * 16 + row16;
    int j = s0 + srow;
    {
      size_t qoff = ((size_t)bh * S_ + j) * D_ + col4;
      float4 xq = *(const float4*)(qa + qoff);
      float4 yq = *(const float4*)(qs + qoff);
      ushort4 rq;
      rq.x = f2bf((xq.x + yq.x) * QSCALE); rq.y = f2bf((xq.y + yq.y) * QSCALE);
      rq.z = f2bf((xq.z + yq.z) * QSCALE); rq.w = f2bf((xq.w + yq.w) * QSCALE);
      *(ushort4*)(qhat + qoff) = rq;
    }
    float4 xv = {0, 0, 0, 0}, yv = {0, 0, 0, 0};
    float4 xk = {0, 0, 0, 0}, yk = {0, 0, 0, 0};
    if (j < C) {
      int src = srcLds[srow];
      size_t off = ((size_t)bh * S_ + src) * D_ + col4;
      xv = *(const float4*)(va + off);
      yv = *(const float4*)(vs + off);
      xk = *(const float4*)(ka + off);
      yk = *(const float4*)(ks + off);
    }
    t[col4 + 0][srow] = f2bf(xv.x + yv.x);
    t[col4 + 1][srow] = f2bf(xv.y + yv.y);
    t[col4 + 2][srow] = f2bf(xv.z + yv.z);
    t[col4 + 3][srow] = f2bf(xv.w + yv.w);
    ushort4 rk;
    rk.x = f2bf(xk.x + yk.x); rk.y = f2bf(xk.y + yk.y);
    rk.z = f2bf(xk.z + yk.z); rk.w = f2bf(xk.w + yk.w);
    *(ushort4*)(khat + ((size_t)bh * S_ + j) * D_ + col4) = rk;
  }
  __syncthreads();
#pragma unroll
  for (int r = 0; r < 2; ++r) {
    int e = (r * 256 + tid) * 8;
    int d = e >> 6, sc = e & 63;
    short8_t v = *(const short8_t*)&t[d][sc];
    *(short8_t*)(vt + ((size_t)bh * D_ + d) * S_ + s0 + sc) = v;
  }
}

// softmax + bf16 pack for one 64-key half (R19-verified math), operates on given score regs
__device__ __forceinline__ void smpack(
    f32x16 (&s0)[2], f32x16 (&s1)[2],
    f32x16 (&a0)[2], f32x16 (&a1)[2], f32x16 (&aS)[2], float (&mr)[2],
    unsigned int (&pk)[2][16], bool dopad, int kvb, int C, int h5) {
#pragma unroll
  for (int qb = 0; qb < 2; ++qb) {
    if (dopad) {
#pragma unroll
      for (int i = 0; i < 16; ++i) {
        int key = kvb + (i & 3) + 8 * (i >> 2) + 4 * h5;
        if (key >= C) s0[qb][i] = -1e9f;
        if (key + 32 >= C) s1[qb][i] = -1e9f;
      }
    }
    float tmx[8];
#pragma unroll
    for (int i = 0; i < 8; ++i)
      tmx[i] = fmaxf(fmaxf(s0[qb][i], s0[qb][i + 8]), fmaxf(s1[qb][i], s1[qb][i + 8]));
#pragma unroll
    for (int i = 0; i < 4; ++i) tmx[i] = fmaxf(tmx[i], tmx[i + 4]);
    float tm = fmaxf(fmaxf(tmx[0], tmx[1]), fmaxf(tmx[2], tmx[3]));
    tm = fmaxf(tm, __shfl_xor(tm, 32));

    if (__any(tm > mr[qb] + 8.0f)) {   // defer-max (T13)
      float mnew = fmaxf(mr[qb], tm);
      float sc = __builtin_amdgcn_exp2f(mr[qb] - mnew);
      mr[qb] = mnew;
      aS[qb][0] *= sc;
#pragma unroll
      for (int i = 0; i < 16; ++i) { a0[qb][i] *= sc; a1[qb][i] *= sc; }
    }

    float m = mr[qb];
#pragma unroll
    for (int i = 0; i < 16; i += 4) {
      s0[qb][i + 0] = __builtin_amdgcn_exp2f(s0[qb][i + 0] - m);
      s0[qb][i + 1] = __builtin_amdgcn_exp2f(s0[qb][i + 1] - m);
      s0[qb][i + 2] = __builtin_amdgcn_exp2f(s0[qb][i + 2] - m);
      s0[qb][i + 3] = __builtin_amdgcn_exp2f(s0[qb][i + 3] - m);
      s1[qb][i + 0] = __builtin_amdgcn_exp2f(s1[qb][i + 0] - m);
      s1[qb][i + 1] = __builtin_amdgcn_exp2f(s1[qb][i + 1] - m);
      s1[qb][i + 2] = __builtin_amdgcn_exp2f(s1[qb][i + 2] - m);
      s1[qb][i + 3] = __builtin_amdgcn_exp2f(s1[qb][i + 3] - m);
    }
#pragma unroll
    for (int rg = 0; rg < 4; ++rg) {
      __hip_bfloat162 a0p = __float22bfloat162_rn({s0[qb][rg * 4 + 0], s0[qb][rg * 4 + 1]});
      __hip_bfloat162 a1p = __float22bfloat162_rn({s0[qb][rg * 4 + 2], s0[qb][rg * 4 + 3]});
      __hip_bfloat162 b0p = __float22bfloat162_rn({s1[qb][rg * 4 + 0], s1[qb][rg * 4 + 1]});
      __hip_bfloat162 b1p = __float22bfloat162_rn({s1[qb][rg * 4 + 2], s1[qb][rg * 4 + 3]});
      pk[qb][rg * 2 + 0] = *(unsigned int*)&a0p;
      pk[qb][rg * 2 + 1] = *(unsigned int*)&a1p;
      pk[qb][8 + rg * 2 + 0] = *(unsigned int*)&b0p;
      pk[qb][8 + rg * 2 + 1] = *(unsigned int*)&b1p;
    }
  }
}

// PV + ones-MFMA row-sum for one half; shfl redistribution (R4-verified mapping)
__device__ __forceinline__ void pvstep(
    const unsigned short* lV, int h, unsigned int (&pk)[2][16],
    f32x16 (&a0)[2], f32x16 (&a1)[2], f32x16 (&aS)[2],
    short8_t ones8, int l31, int h5, int rsw) {
  __builtin_amdgcn_s_setprio(1);
#pragma unroll
  for (int kt = 0; kt < 4; ++kt) {
    const int n = kt >> 1, k1 = kt & 1;
    int gcol = ((h * 8) | ((2 * kt + h5) ^ rsw)) * 8;
    short8_t vf0 = *(const short8_t*)&lV[l31 * KVB + gcol];
    short8_t vf1 = *(const short8_t*)&lV[(32 + l31) * KVB + gcol];
#pragma unroll
    for (int qb = 0; qb < 2; ++qb) {
      unsigned int sA = pk[qb][n * 8 + (2 * k1 + h5) * 2 + 0];
      unsigned int sB = pk[qb][n * 8 + (2 * k1 + h5) * 2 + 1];
      unsigned int xA = pk[qb][n * 8 + (2 * k1 + (h5 ^ 1)) * 2 + 0];
      unsigned int xB = pk[qb][n * 8 + (2 * k1 + (h5 ^ 1)) * 2 + 1];
      unsigned int pA = (unsigned int)__shfl_xor((int)xA, 32);
      unsigned int pB = (unsigned int)__shfl_xor((int)xB, 32);
      union { unsigned int u[4]; short8_t v; } bb;
      bb.u[0] = h5 ? pA : sA;
      bb.u[1] = h5 ? pB : sB;
      bb.u[2] = h5 ? sA : pA;
      bb.u[3] = h5 ? sB : pB;
      a0[qb] = __builtin_amdgcn_mfma_f32_32x32x16_bf16(vf0, bb.v, a0[qb], 0, 0, 0);
      a1[qb] = __builtin_amdgcn_mfma_f32_32x32x16_bf16(vf1, bb.v, a1[qb], 0, 0, 0);
      aS[qb] = __builtin_amdgcn_mfma_f32_32x32x16_bf16(ones8, bb.v, aS[qb], 0, 0, 0);
    }
  }
  __builtin_amdgcn_s_setprio(0);
}

// Flash attention, 512 threads = 8 waves: waves 0-3 chunk 0, waves 4-7 chunk 1.
// R19-verified math; cross-half pipeline: QK(h1) issued before PV(h0) so SM(h1)'s
// VALU overlaps PV(h0)'s MFMA cluster (separate pipes, m114).
__global__ __launch_bounds__(512, 1) void attn_kernel(
    const unsigned short* __restrict__ Qb, const unsigned short* __restrict__ Kb,
    const unsigned short* __restrict__ Vt, const int* __restrict__ cnt,
    float* __restrict__ out) {
  __shared__ __align__(16) unsigned char smem[131072];
  unsigned short* lKp = (unsigned short*)smem;            // [chunk][buf][8192]
  unsigned short* lVp = lKp + 32768;                      // [chunk][buf][8192]

  const int tid  = threadIdx.x;
  const int wave = tid >> 6;
  const int chid = wave >> 2;          // 0 or 1: KV chunk
  const int wq   = wave & 3;           // q-position wave within chunk
  const int ctid = tid & 255;
  const int lane = tid & 63;
  const int l31  = lane & 31;
  const int h5   = lane >> 5;
  const int rsw  = l31 & 7;
  const int bh   = blockIdx.y;
  const int qrow0 = blockIdx.x * QBLK + wq * QW + l31;
  const int b    = bh >> 3;
  const int C    = cnt[b];
  const int NTt  = (C + KVB - 1) / KVB;
  const int tpc  = (NTt + NCH - 1) / NCH;
  const int ts   = chid * tpc;
  const int te   = (ts + tpc < NTt) ? (ts + tpc) : NTt;

  short8_t qf[2][4];
#pragma unroll
  for (int qb = 0; qb < 2; ++qb) {
    const unsigned short* qp = Qb + ((size_t)bh * S_ + qrow0 + 32 * qb) * D_ + h5 * 8;
#pragma unroll
    for (int t4 = 0; t4 < 4; ++t4) qf[qb][t4] = *(const short8_t*)(qp + t4 * 16);
  }

  short8_t ones8;
#pragma unroll
  for (int i = 0; i < 8; ++i) ones8[i] = (short)0x3F80;

  const unsigned short* gk0 = Kb + (size_t)bh * S_ * D_;
  const unsigned short* gv0 = Vt + (size_t)bh * D_ * S_;

  int srcK[4], srcV[4], ldsB[4];
#pragma unroll
  for (int r2 = 0; r2 < 4; ++r2) {
    int c = r2 * 256 + ctid;
    int rowK = c >> 3, gK = (c & 7) ^ (rowK & 7);
    srcK[r2] = rowK * 64 + gK * 8;
    int rowV = c >> 4, gg = c & 15;
    int swg = (gg & 8) | ((gg & 7) ^ (rowV & 7));
    srcV[r2] = rowV * S_ + swg * 8;
    ldsB[r2] = r2 * 2048 + wq * 512;
  }
  unsigned short* lK0 = lKp + chid * 2 * 8192;
  unsigned short* lV0 = lVp + chid * 2 * 8192;

  f32x16 acc0[2], acc1[2], accS[2];
  float mrow[2];
#pragma unroll
  for (int qb = 0; qb < 2; ++qb) {
    acc0[qb] = (f32x16)(0.0f); acc1[qb] = (f32x16)(0.0f); accS[qb] = (f32x16)(0.0f);
    mrow[qb] = -1e30f;
  }

  if (ts < te) {
#pragma unroll
    for (int r2 = 0; r2 < 4; ++r2) {
      glds16(gk0 + (size_t)ts * KVB * D_ + srcK[r2], lK0 + ldsB[r2]);
      glds16(gv0 + ts * KVB + srcV[r2], lV0 + ldsB[r2]);
    }
  }

  for (int it = 0; it < tpc; ++it) {     // uniform loop count; barriers unconditional
    const int t = ts + it;
    const int cur = it & 1;
    if (t + 1 < te) {
#pragma unroll
      for (int r2 = 0; r2 < 4; ++r2) {
        glds16(gk0 + (size_t)(t + 1) * KVB * D_ + srcK[r2], lK0 + (cur ^ 1) * 8192 + ldsB[r2]);
        glds16(gv0 + (t + 1) * KVB + srcV[r2], lV0 + (cur ^ 1) * 8192 + ldsB[r2]);
      }
      asm volatile("s_waitcnt vmcnt(8)" ::: "memory");
    } else {
      asm volatile("s_waitcnt vmcnt(0)" ::: "memory");
    }
    __builtin_amdgcn_s_barrier();
    __builtin_amdgcn_sched_barrier(0);

    if (t < te) {
      const unsigned short* lK = lK0 + cur * 8192;
      const unsigned short* lV = lV0 + cur * 8192;
      const bool tail = (t == NTt - 1);
      unsigned int pkw[2][16];

      // ---- QK half 0 -> sv
      f32x16 sv0[2], sv1[2];
#pragma unroll
      for (int qb = 0; qb < 2; ++qb) { sv0[qb] = (f32x16)(0.0f); sv1[qb] = (f32x16)(0.0f); }
      __builtin_amdgcn_s_setprio(1);
#pragma unroll
      for (int t4 = 0; t4 < 4; ++t4) {
        int g = ((2 * t4 + h5) ^ rsw) * 8;
        short8_t kf0 = *(const short8_t*)&lK[l31 * 64 + g];
        short8_t kf1 = *(const short8_t*)&lK[(32 + l31) * 64 + g];
        sv0[0] = __builtin_amdgcn_mfma_f32_32x32x16_bf16(kf0, qf[0][t4], sv0[0], 0, 0, 0);
        sv0[1] = __builtin_amdgcn_mfma_f32_32x32x16_bf16(kf0, qf[1][t4], sv0[1], 0, 0, 0);
        sv1[0] = __builtin_amdgcn_mfma_f32_32x32x16_bf16(kf1, qf[0][t4], sv1[0], 0, 0, 0);
        sv1[1] = __builtin_amdgcn_mfma_f32_32x32x16_bf16(kf1, qf[1][t4], sv1[1], 0, 0, 0);
      }
      __builtin_amdgcn_s_setprio(0);

      // ---- softmax+pack half 0 -> pkw
      smpack(sv0, sv1, acc0, acc1, accS, mrow, pkw, tail, t * KVB, C, h5);

      // ---- QK half 1 -> tv (issued BEFORE PV(h0): SM(h1) VALU overlaps PV(h0) MFMA)
      f32x16 tv0[2], tv1[2];
#pragma unroll
      for (int qb = 0; qb < 2; ++qb) { tv0[qb] = (f32x16)(0.0f); tv1[qb] = (f32x16)(0.0f); }
      __builtin_amdgcn_s_setprio(1);
#pragma unroll
      for (int t4 = 0; t4 < 4; ++t4) {
        int g = ((2 * t4 + h5) ^ rsw) * 8;
        short8_t kf0 = *(const short8_t*)&lK[(64 + l31) * 64 + g];
        short8_t kf1 = *(const short8_t*)&lK[(64 + 32 + l31) * 64 + g];
        tv0[0] = __builtin_amdgcn_mfma_f32_32x32x16_bf16(kf0, qf[0][t4], tv0[0], 0, 0, 0);
        tv0[1] = __builtin_amdgcn_mfma_f32_32x32x16_bf16(kf0, qf[1][t4], tv0[1], 0, 0, 0);
        tv1[0] = __builtin_amdgcn_mfma_f32_32x32x16_bf16(kf1, qf[0][t4], tv1[0], 0, 0, 0);
        tv1[1] = __builtin_amdgcn_mfma_f32_32x32x16_bf16(kf1, qf[1][t4], tv1[1], 0, 0, 0);
      }
      __builtin_amdgcn_s_setprio(0);

      // ---- PV half 0 (consumes pkw; independent of tv)
      pvstep(lV, 0, pkw, acc0, acc1, accS, ones8, l31, h5, rsw);

      // ---- softmax+pack half 1 -> pkw (VALU; overlaps PV(h0) MFMA above)
      smpack(tv0, tv1, acc0, acc1, accS, mrow, pkw, tail, t * KVB + 64, C, h5);

      // ---- PV half 1
      pvstep(lV, 1, pkw, acc0, acc1, accS, ones8, l31, h5, rsw);
    }

    __builtin_amdgcn_sched_barrier(0);
    __builtin_amdgcn_s_barrier();
  }

  // ---- in-LDS combine: chunk 1 publishes partials, chunk 0 merges + writes out
  float* part = (float*)smem;                 // [256 rows][72] fp32
  float2* mlsh = (float2*)(smem + 73728);     // [256] (m, l)
  __syncthreads();

  if (chid == 1) {
#pragma unroll
    for (int qb = 0; qb < 2; ++qb) {
      int rl = wq * 64 + qb * 32 + l31;
      float* pr = part + rl * 72;
#pragma unroll
      for (int rg = 0; rg < 4; ++rg) {
        float4 o0, o1;
        o0.x = acc0[qb][rg * 4 + 0]; o0.y = acc0[qb][rg * 4 + 1];
        o0.z = acc0[qb][rg * 4 + 2]; o0.w = acc0[qb][rg * 4 + 3];
        o1.x = acc1[qb][rg * 4 + 0]; o1.y = acc1[qb][rg * 4 + 1];
        o1.z = acc1[qb][rg * 4 + 2]; o1.w = acc1[qb][rg * 4 + 3];
        *(float4*)(pr + rg * 8 + h5 * 4) = o0;
        *(float4*)(pr + 32 + rg * 8 + h5 * 4) = o1;
      }
      if (h5 == 0) { float2 st; st.x = mrow[qb]; st.y = accS[qb][0]; mlsh[rl] = st; }
    }
  }
  __syncthreads();
  if (chid == 0) {
#pragma unroll
    for (int qb = 0; qb < 2; ++qb) {
      int rl = wq * 64 + qb * 32 + l31;
      float2 pml = mlsh[rl];
      float m0 = mrow[qb], l0 = accS[qb][0];
      float M = fmaxf(m0, pml.x);
      float w0 = exp2f(m0 - M), w1 = exp2f(pml.x - M);
      float inv = 1.0f / (l0 * w0 + pml.y * w1);
      w0 *= inv; w1 *= inv;
      const float* pr = part + rl * 72;
      float* op = out + ((size_t)bh * S_ + qrow0 + 32 * qb) * D_;
#pragma unroll
      for (int rg = 0; rg < 4; ++rg) {
        float4 p0v = *(const float4*)(pr + rg * 8 + h5 * 4);
        float4 p1v = *(const float4*)(pr + 32 + rg * 8 + h5 * 4);
        float4 o0, o1;
        o0.x = acc0[qb][rg * 4 + 0] * w0 + p0v.x * w1;
        o0.y = acc0[qb][rg * 4 + 1] * w0 + p0v.y * w1;
        o0.z = acc0[qb][rg * 4 + 2] * w0 + p0v.z * w1;
        o0.w = acc0[qb][rg * 4 + 3] * w0 + p0v.w * w1;
        o1.x = acc1[qb][rg * 4 + 0] * w0 + p1v.x * w1;
        o1.y = acc1[qb][rg * 4 + 1] * w0 + p1v.y * w1;
        o1.z = acc1[qb][rg * 4 + 2] * w0 + p1v.z * w1;
        o1.w = acc1[qb][rg * 4 + 3] * w0 + p1v.w * w1;
        *(float4*)(op + rg * 8 + h5 * 4) = o0;
        *(float4*)(op + 32 + rg * 8 + h5 * 4) = o1;
      }
    }
  }
}

extern "C" void kernel_launch(void* const* d_in, const int* in_sizes, int n_in,
                              void* d_out, int out_size, void* d_ws, size_t ws_size,
                              hipStream_t stream) {
  const float* q_a = (const float*)d_in[0];
  const float* k_a = (const float*)d_in[1];
  const float* v_a = (const float*)d_in[2];
  const float* q_s = (const float*)d_in[3];
  const float* k_s = (const float*)d_in[4];
  const float* v_s = (const float*)d_in[5];
  const int*   mask = (const int*)d_in[6];
  float* out = (float*)d_out;
  (void)in_sizes; (void)n_in; (void)out_size; (void)ws_size;

  const int N = BH_ * S_ * D_;   // 4,194,304
  unsigned short* qhat = (unsigned short*)d_ws;
  unsigned short* khat = qhat + N;
  unsigned short* vt   = khat + N;
  int* cnt = (int*)(vt + N);             // 4 ints

  {
    dim3 g(S_ / 64, BH_);
    kvgather_kernel<<<g, 256, 0, stream>>>(k_a, k_s, v_a, v_s, q_a, q_s, mask, cnt,
                                           qhat, khat, vt);
  }
  {
    dim3 g(S_ / QBLK, BH_);
    attn_kernel<<<g, 512, 0, stream>>>(qhat, khat, vt, cnt, out);
  }
}

// Round 22
// 109.607 us; speedup vs baseline: 1.4191x; 1.4191x over previous
//
#include <hip/hip_runtime.h>
#include <hip/hip_bf16.h>

// (B,H,S,D) = (2,8,4096,64)
#define S_   4096
#define D_   64
#define BH_  16
#define QW   64        // q rows per wave (two 32-col MFMA blocks)
#define QBLK 256       // q rows per block
#define KVB  128       // keys per staged tile (two 64-key halves per barrier)
#define NCH  2         // kv chunks (wave-halves of one block)

typedef __attribute__((ext_vector_type(8)))  short short8_t;   // 8 bf16 (MFMA A/B frag)
typedef __attribute__((ext_vector_type(16))) float f32x16;     // 32x32 MFMA C/D frag
#define QSCALE 0.18033688011112042f   /* (1/8)*log2(e): scores in log2 domain */

__device__ __forceinline__ unsigned short f2bf(float f) {
  unsigned u = __float_as_uint(f);
  u += 0x7fffu + ((u >> 16) & 1u);   // RTNE
  return (unsigned short)(u >> 16);
}

__device__ __forceinline__ void glds16(const unsigned short* g, unsigned short* l) {
  __builtin_amdgcn_global_load_lds(
      (const __attribute__((address_space(1))) unsigned int*)g,
      (__attribute__((address_space(3))) unsigned int*)l, 16, 0, 0);
}

// fused: per-batch mask scan (compact) + K/V gather + Q add/scale convert + V transpose.
__global__ void kvgather_kernel(const float* __restrict__ ka, const float* __restrict__ ks,
                                const float* __restrict__ va, const float* __restrict__ vs,
                                const float* __restrict__ qa, const float* __restrict__ qs,
                                const int* __restrict__ mask, int* __restrict__ cnt,
                                unsigned short* __restrict__ qhat,
                                unsigned short* __restrict__ khat,
                                unsigned short* __restrict__ vt) {
  __shared__ int ps[256];
  __shared__ int srcLds[64];
  __shared__ __align__(16) unsigned short t[D_][72];
  const int bh = blockIdx.y, b = bh >> 3;
  const int s0 = blockIdx.x * 64;
  const int tid = threadIdx.x;

  const int* mb = mask + (size_t)b * S_;
  int m[16], c = 0;
  const int base = tid * 16;
#pragma unroll
  for (int i = 0; i < 16; ++i) { m[i] = mb[base + i]; c += (m[i] != 0); }
  ps[tid] = c;
  __syncthreads();
  for (int off = 1; off < 256; off <<= 1) {   // Hillis-Steele inclusive scan
    int add = (tid >= off) ? ps[tid - off] : 0;
    __syncthreads();
    ps[tid] += add;
    __syncthreads();
  }
  const int C = ps[255];
  int pos = ps[tid] - c;   // exclusive prefix
#pragma unroll
  for (int i = 0; i < 16; ++i) {
    if (m[i]) {
      int r = pos++;
      if (r >= s0 && r < s0 + 64) srcLds[r - s0] = base + i;
    }
  }
  if (tid == 0 && blockIdx.x == 0 && (bh & 7) == 0) cnt[b] = C;
  __syncthreads();

  const int row16 = tid >> 4;
  const int col4  = (tid & 15) * 4;
#pragma unroll
  for (int p = 0; p < 4; ++p) {
    int srow = p * 16 + row16;
    int j = s0 + srow;
    {
      size_t qoff = ((size_t)bh * S_ + j) * D_ + col4;
      float4 xq = *(const float4*)(qa + qoff);
      float4 yq = *(const float4*)(qs + qoff);
      ushort4 rq;
      rq.x = f2bf((xq.x + yq.x) * QSCALE); rq.y = f2bf((xq.y + yq.y) * QSCALE);
      rq.z = f2bf((xq.z + yq.z) * QSCALE); rq.w = f2bf((xq.w + yq.w) * QSCALE);
      *(ushort4*)(qhat + qoff) = rq;
    }
    float4 xv = {0, 0, 0, 0}, yv = {0, 0, 0, 0};
    float4 xk = {0, 0, 0, 0}, yk = {0, 0, 0, 0};
    if (j < C) {
      int src = srcLds[srow];
      size_t off = ((size_t)bh * S_ + src) * D_ + col4;
      xv = *(const float4*)(va + off);
      yv = *(const float4*)(vs + off);
      xk = *(const float4*)(ka + off);
      yk = *(const float4*)(ks + off);
    }
    t[col4 + 0][srow] = f2bf(xv.x + yv.x);
    t[col4 + 1][srow] = f2bf(xv.y + yv.y);
    t[col4 + 2][srow] = f2bf(xv.z + yv.z);
    t[col4 + 3][srow] = f2bf(xv.w + yv.w);
    ushort4 rk;
    rk.x = f2bf(xk.x + yk.x); rk.y = f2bf(xk.y + yk.y);
    rk.z = f2bf(xk.z + yk.z); rk.w = f2bf(xk.w + yk.w);
    *(ushort4*)(khat + ((size_t)bh * S_ + j) * D_ + col4) = rk;
  }
  __syncthreads();
#pragma unroll
  for (int r = 0; r < 2; ++r) {
    int e = (r * 256 + tid) * 8;
    int d = e >> 6, sc = e & 63;
    short8_t v = *(const short8_t*)&t[d][sc];
    *(short8_t*)(vt + ((size_t)bh * D_ + d) * S_ + s0 + sc) = v;
  }
}

// Flash attention, 512 threads = 8 waves: waves 0-3 chunk 0, waves 4-7 chunk 1.
// Per chunk: R18-verified math (swapped QK^T 32x32x16, ones-MFMA row-sum,
// counted-vmcnt double-buffer, two 64-key halves per barrier). In-LDS combine epilogue.
__global__ __launch_bounds__(512, 1) void attn_kernel(
    const unsigned short* __restrict__ Qb, const unsigned short* __restrict__ Kb,
    const unsigned short* __restrict__ Vt, const int* __restrict__ cnt,
    float* __restrict__ out) {
  // 128KB LDS pool: per-chunk K/V double buffers; reused as fp32 partial tile in epilogue
  __shared__ __align__(16) unsigned char smem[131072];
  unsigned short* lKp = (unsigned short*)smem;            // [chunk][buf][8192]
  unsigned short* lVp = lKp + 32768;                      // [chunk][buf][8192]

  const int tid  = threadIdx.x;
  const int wave = tid >> 6;
  const int chid = wave >> 2;          // 0 or 1: KV chunk
  const int wq   = wave & 3;           // q-position wave within chunk
  const int ctid = tid & 255;          // tid within chunk half
  const int lane = tid & 63;
  const int l31  = lane & 31;
  const int h5   = lane >> 5;
  const int rsw  = l31 & 7;
  const int bh   = blockIdx.y;
  const int qrow0 = blockIdx.x * QBLK + wq * QW + l31;   // q-block 0; +32 for q-block 1
  const int b    = bh >> 3;
  const int C    = cnt[b];
  const int NTt  = (C + KVB - 1) / KVB;          // total 128-key tiles
  const int tpc  = (NTt + NCH - 1) / NCH;        // tiles per chunk (uniform loop count)
  const int ts   = chid * tpc;
  const int te   = (ts + tpc < NTt) ? (ts + tpc) : NTt;

  // Q fragments (B-operand)
  short8_t qf[2][4];
#pragma unroll
  for (int qb = 0; qb < 2; ++qb) {
    const unsigned short* qp = Qb + ((size_t)bh * S_ + qrow0 + 32 * qb) * D_ + h5 * 8;
#pragma unroll
    for (int t4 = 0; t4 < 4; ++t4) qf[qb][t4] = *(const short8_t*)(qp + t4 * 16);
  }

  short8_t ones8;
#pragma unroll
  for (int i = 0; i < 8; ++i) ones8[i] = (short)0x3F80;

  const unsigned short* gk0 = Kb + (size_t)bh * S_ * D_;
  const unsigned short* gv0 = Vt + (size_t)bh * D_ * S_;

  // staging geometry (per chunk: 1024 16B-chunks/tile/tensor; 4 per thread of 256)
  int srcK[4], srcV[4], ldsB[4];
#pragma unroll
  for (int r2 = 0; r2 < 4; ++r2) {
    int c = r2 * 256 + ctid;
    int rowK = c >> 3, gK = (c & 7) ^ (rowK & 7);
    srcK[r2] = rowK * 64 + gK * 8;
    int rowV = c >> 4, gg = c & 15;
    int swg = (gg & 8) | ((gg & 7) ^ (rowV & 7));
    srcV[r2] = rowV * S_ + swg * 8;
    ldsB[r2] = r2 * 2048 + wq * 512;   // wave-uniform base within a chunk buffer
  }
  unsigned short* lK0 = lKp + chid * 2 * 8192;   // + buf*8192
  unsigned short* lV0 = lVp + chid * 2 * 8192;

  f32x16 acc0[2], acc1[2], accS[2];
  float mrow[2];
#pragma unroll
  for (int qb = 0; qb < 2; ++qb) {
    acc0[qb] = (f32x16)(0.0f); acc1[qb] = (f32x16)(0.0f); accS[qb] = (f32x16)(0.0f);
    mrow[qb] = -1e30f;
  }

  // prologue: issue tile-ts loads into buf0 (8 per wave); no drain here
  if (ts < te) {
#pragma unroll
    for (int r2 = 0; r2 < 4; ++r2) {
      glds16(gk0 + (size_t)ts * KVB * D_ + srcK[r2], lK0 + ldsB[r2]);
      glds16(gv0 + ts * KVB + srcV[r2], lV0 + ldsB[r2]);
    }
  }

  for (int it = 0; it < tpc; ++it) {     // uniform loop count; barriers unconditional
    const int t = ts + it;
    const int cur = it & 1;
    if (t + 1 < te) {
#pragma unroll
      for (int r2 = 0; r2 < 4; ++r2) {
        glds16(gk0 + (size_t)(t + 1) * KVB * D_ + srcK[r2], lK0 + (cur ^ 1) * 8192 + ldsB[r2]);
        glds16(gv0 + (t + 1) * KVB + srcV[r2], lV0 + (cur ^ 1) * 8192 + ldsB[r2]);
      }
      asm volatile("s_waitcnt vmcnt(8)" ::: "memory");
    } else {
      asm volatile("s_waitcnt vmcnt(0)" ::: "memory");
    }
    __builtin_amdgcn_s_barrier();
    __builtin_amdgcn_sched_barrier(0);

    if (t < te) {
      const unsigned short* lK = lK0 + cur * 8192;
      const unsigned short* lV = lV0 + cur * 8192;
#pragma unroll
      for (int h = 0; h < 2; ++h) {
        f32x16 sv0[2], sv1[2];
#pragma unroll
        for (int qb = 0; qb < 2; ++qb) { sv0[qb] = (f32x16)(0.0f); sv1[qb] = (f32x16)(0.0f); }
        __builtin_amdgcn_s_setprio(1);
#pragma unroll
        for (int t4 = 0; t4 < 4; ++t4) {
          int g = ((2 * t4 + h5) ^ rsw) * 8;
          short8_t kf0 = *(const short8_t*)&lK[(h * 64 + l31) * 64 + g];
          short8_t kf1 = *(const short8_t*)&lK[(h * 64 + 32 + l31) * 64 + g];
          sv0[0] = __builtin_amdgcn_mfma_f32_32x32x16_bf16(kf0, qf[0][t4], sv0[0], 0, 0, 0);
          sv0[1] = __builtin_amdgcn_mfma_f32_32x32x16_bf16(kf0, qf[1][t4], sv0[1], 0, 0, 0);
          sv1[0] = __builtin_amdgcn_mfma_f32_32x32x16_bf16(kf1, qf[0][t4], sv1[0], 0, 0, 0);
          sv1[1] = __builtin_amdgcn_mfma_f32_32x32x16_bf16(kf1, qf[1][t4], sv1[1], 0, 0, 0);
        }
        __builtin_amdgcn_s_setprio(0);

        if (t == NTt - 1) {   // tail: pad keys -> -1e9
          int kvb = t * KVB + h * 64;
#pragma unroll
          for (int i = 0; i < 16; ++i) {
            int key = kvb + (i & 3) + 8 * (i >> 2) + 4 * h5;
#pragma unroll
            for (int qb = 0; qb < 2; ++qb) {
              if (key >= C) sv0[qb][i] = -1e9f;
              if (key + 32 >= C) sv1[qb][i] = -1e9f;
            }
          }
        }

        unsigned int pkw[2][16];
#pragma unroll
        for (int qb = 0; qb < 2; ++qb) {
          float tmx[8];
#pragma unroll
          for (int i = 0; i < 8; ++i)
            tmx[i] = fmaxf(fmaxf(sv0[qb][i], sv0[qb][i + 8]),
                           fmaxf(sv1[qb][i], sv1[qb][i + 8]));
#pragma unroll
          for (int i = 0; i < 4; ++i) tmx[i] = fmaxf(tmx[i], tmx[i + 4]);
          float tm = fmaxf(fmaxf(tmx[0], tmx[1]), fmaxf(tmx[2], tmx[3]));
          tm = fmaxf(tm, __shfl_xor(tm, 32));

          if (__any(tm > mrow[qb] + 8.0f)) {   // defer-max (T13)
            float mnew = fmaxf(mrow[qb], tm);
            float sc = __builtin_amdgcn_exp2f(mrow[qb] - mnew);
            mrow[qb] = mnew;
            accS[qb][0] *= sc;
#pragma unroll
            for (int i = 0; i < 16; ++i) { acc0[qb][i] *= sc; acc1[qb][i] *= sc; }
          }

          float m = mrow[qb];
#pragma unroll
          for (int i = 0; i < 16; i += 4) {
            sv0[qb][i + 0] = __builtin_amdgcn_exp2f(sv0[qb][i + 0] - m);
            sv0[qb][i + 1] = __builtin_amdgcn_exp2f(sv0[qb][i + 1] - m);
            sv0[qb][i + 2] = __builtin_amdgcn_exp2f(sv0[qb][i + 2] - m);
            sv0[qb][i + 3] = __builtin_amdgcn_exp2f(sv0[qb][i + 3] - m);
            sv1[qb][i + 0] = __builtin_amdgcn_exp2f(sv1[qb][i + 0] - m);
            sv1[qb][i + 1] = __builtin_amdgcn_exp2f(sv1[qb][i + 1] - m);
            sv1[qb][i + 2] = __builtin_amdgcn_exp2f(sv1[qb][i + 2] - m);
            sv1[qb][i + 3] = __builtin_amdgcn_exp2f(sv1[qb][i + 3] - m);
          }

#pragma unroll
          for (int rg = 0; rg < 4; ++rg) {
            __hip_bfloat162 a0 = __float22bfloat162_rn({sv0[qb][rg * 4 + 0], sv0[qb][rg * 4 + 1]});
            __hip_bfloat162 a1 = __float22bfloat162_rn({sv0[qb][rg * 4 + 2], sv0[qb][rg * 4 + 3]});
            __hip_bfloat162 b0 = __float22bfloat162_rn({sv1[qb][rg * 4 + 0], sv1[qb][rg * 4 + 1]});
            __hip_bfloat162 b1 = __float22bfloat162_rn({sv1[qb][rg * 4 + 2], sv1[qb][rg * 4 + 3]});
            pkw[qb][rg * 2 + 0] = *(unsigned int*)&a0;
            pkw[qb][rg * 2 + 1] = *(unsigned int*)&a1;
            pkw[qb][8 + rg * 2 + 0] = *(unsigned int*)&b0;
            pkw[qb][8 + rg * 2 + 1] = *(unsigned int*)&b1;
          }
        }

        // O^T += V^T P (+ row-sum ones-MFMA); shfl redistribution (R4-verified)
        __builtin_amdgcn_s_setprio(1);
#pragma unroll
        for (int kt = 0; kt < 4; ++kt) {
          const int n = kt >> 1, k1 = kt & 1;
          int gcol = ((h * 8) | ((2 * kt + h5) ^ rsw)) * 8;
          short8_t vf0 = *(const short8_t*)&lV[l31 * KVB + gcol];
          short8_t vf1 = *(const short8_t*)&lV[(32 + l31) * KVB + gcol];
#pragma unroll
          for (int qb = 0; qb < 2; ++qb) {
            unsigned int sA = pkw[qb][n * 8 + (2 * k1 + h5) * 2 + 0];
            unsigned int sB = pkw[qb][n * 8 + (2 * k1 + h5) * 2 + 1];
            unsigned int xA = pkw[qb][n * 8 + (2 * k1 + (h5 ^ 1)) * 2 + 0];
            unsigned int xB = pkw[qb][n * 8 + (2 * k1 + (h5 ^ 1)) * 2 + 1];
            unsigned int pA = (unsigned int)__shfl_xor((int)xA, 32);
            unsigned int pB = (unsigned int)__shfl_xor((int)xB, 32);
            union { unsigned int u[4]; short8_t v; } bb;
            bb.u[0] = h5 ? pA : sA;
            bb.u[1] = h5 ? pB : sB;
            bb.u[2] = h5 ? sA : pA;
            bb.u[3] = h5 ? sB : pB;
            acc0[qb] = __builtin_amdgcn_mfma_f32_32x32x16_bf16(vf0, bb.v, acc0[qb], 0, 0, 0);
            acc1[qb] = __builtin_amdgcn_mfma_f32_32x32x16_bf16(vf1, bb.v, acc1[qb], 0, 0, 0);
            accS[qb] = __builtin_amdgcn_mfma_f32_32x32x16_bf16(ones8, bb.v, accS[qb], 0, 0, 0);
          }
        }
        __builtin_amdgcn_s_setprio(0);
      }
    }

    __builtin_amdgcn_sched_barrier(0);
    __builtin_amdgcn_s_barrier();   // all waves done with buf[cur] before next glds
  }

  // ---- in-LDS combine: chunk 1 publishes partials, chunk 0 merges + writes out
  float* part = (float*)smem;                 // [256 rows][72] fp32 (aligned float4 rows)
  float2* mlsh = (float2*)(smem + 73728);     // [256] (m, l)
  __syncthreads();                            // staging LDS dead; safe to overwrite

  if (chid == 1) {
#pragma unroll
    for (int qb = 0; qb < 2; ++qb) {
      int rl = wq * 64 + qb * 32 + l31;
      float* pr = part + rl * 72;
#pragma unroll
      for (int rg = 0; rg < 4; ++rg) {
        float4 o0, o1;
        o0.x = acc0[qb][rg * 4 + 0]; o0.y = acc0[qb][rg * 4 + 1];
        o0.z = acc0[qb][rg * 4 + 2]; o0.w = acc0[qb][rg * 4 + 3];
        o1.x = acc1[qb][rg * 4 + 0]; o1.y = acc1[qb][rg * 4 + 1];
        o1.z = acc1[qb][rg * 4 + 2]; o1.w = acc1[qb][rg * 4 + 3];
        *(float4*)(pr + rg * 8 + h5 * 4) = o0;
        *(float4*)(pr + 32 + rg * 8 + h5 * 4) = o1;
      }
      if (h5 == 0) { float2 st; st.x = mrow[qb]; st.y = accS[qb][0]; mlsh[rl] = st; }
    }
  }
  __syncthreads();
  if (chid == 0) {
#pragma unroll
    for (int qb = 0; qb < 2; ++qb) {
      int rl = wq * 64 + qb * 32 + l31;
      float2 pml = mlsh[rl];
      float m0 = mrow[qb], l0 = accS[qb][0];
      float M = fmaxf(m0, pml.x);
      float w0 = exp2f(m0 - M), w1 = exp2f(pml.x - M);
      float inv = 1.0f / (l0 * w0 + pml.y * w1);
      w0 *= inv; w1 *= inv;
      const float* pr = part + rl * 72;
      float* op = out + ((size_t)bh * S_ + qrow0 + 32 * qb) * D_;
#pragma unroll
      for (int rg = 0; rg < 4; ++rg) {
        float4 p0v = *(const float4*)(pr + rg * 8 + h5 * 4);
        float4 p1v = *(const float4*)(pr + 32 + rg * 8 + h5 * 4);
        float4 o0, o1;
        o0.x = acc0[qb][rg * 4 + 0] * w0 + p0v.x * w1;
        o0.y = acc0[qb][rg * 4 + 1] * w0 + p0v.y * w1;
        o0.z = acc0[qb][rg * 4 + 2] * w0 + p0v.z * w1;
        o0.w = acc0[qb][rg * 4 + 3] * w0 + p0v.w * w1;
        o1.x = acc1[qb][rg * 4 + 0] * w0 + p1v.x * w1;
        o1.y = acc1[qb][rg * 4 + 1] * w0 + p1v.y * w1;
        o1.z = acc1[qb][rg * 4 + 2] * w0 + p1v.z * w1;
        o1.w = acc1[qb][rg * 4 + 3] * w0 + p1v.w * w1;
        *(float4*)(op + rg * 8 + h5 * 4) = o0;
        *(float4*)(op + 32 + rg * 8 + h5 * 4) = o1;
      }
    }
  }
}

extern "C" void kernel_launch(void* const* d_in, const int* in_sizes, int n_in,
                              void* d_out, int out_size, void* d_ws, size_t ws_size,
                              hipStream_t stream) {
  const float* q_a = (const float*)d_in[0];
  const float* k_a = (const float*)d_in[1];
  const float* v_a = (const float*)d_in[2];
  const float* q_s = (const float*)d_in[3];
  const float* k_s = (const float*)d_in[4];
  const float* v_s = (const float*)d_in[5];
  const int*   mask = (const int*)d_in[6];
  float* out = (float*)d_out;
  (void)in_sizes; (void)n_in; (void)out_size; (void)ws_size;

  const int N = BH_ * S_ * D_;   // 4,194,304
  unsigned short* qhat = (unsigned short*)d_ws;
  unsigned short* khat = qhat + N;
  unsigned short* vt   = khat + N;
  int* cnt = (int*)(vt + N);             // 4 ints

  {
    dim3 g(S_ / 64, BH_);
    kvgather_kernel<<<g, 256, 0, stream>>>(k_a, k_s, v_a, v_s, q_a, q_s, mask, cnt,
                                           qhat, khat, vt);
  }
  {
    dim3 g(S_ / QBLK, BH_);
    attn_kernel<<<g, 512, 0, stream>>>(qhat, khat, vt, cnt, out);
  }
}